// Round 3
// baseline (1037.225 us; speedup 1.0000x reference)
//
#include <hip/hip_runtime.h>

#define HW (128*128)

typedef __bf16 bf16x8 __attribute__((ext_vector_type(8)));
typedef float  float4v __attribute__((ext_vector_type(4)));
typedef int    int4v   __attribute__((ext_vector_type(4)));
typedef int    int2v   __attribute__((ext_vector_type(2)));

static __device__ __forceinline__ short f2bf(float f) {
    unsigned u = __float_as_uint(f);
    unsigned r = (u + 0x7FFFu + ((u >> 16) & 1u)) >> 16;
    return (short)(r & 0xFFFFu);
}
static __device__ __forceinline__ int pack2(short a, short b) {
    return (int)((unsigned short)a | ((unsigned)(unsigned short)b << 16));
}
// async global->LDS, 16B per lane; LDS dest = wave-uniform base + lane*16
static __device__ __forceinline__ void async_cp16(const void* g, void* l) {
    __builtin_amdgcn_global_load_lds(
        (const __attribute__((address_space(1))) unsigned int*)g,
        (__attribute__((address_space(3))) unsigned int*)l, 16, 0, 0);
}

// ---------------------------------------------------------------------------
// prep: pre-swizzled bf16 weight streams (LDS-chunk order per K-step), zero
// buffer, h2p halo zeroing.
// Swizzle rule (64B rows, 4 chunks): LDS chunk (n,c) holds k-chunk c^((n>>1)&3).
// ---------------------------------------------------------------------------
__global__ __launch_bounds__(256) void prep_weights(
    const float* __restrict__ W1, const float* __restrict__ W2,
    const float* __restrict__ W3,
    short* __restrict__ W1sw, short* __restrict__ W2sw, short* __restrict__ W3sw,
    char* __restrict__ h2p, int4v* __restrict__ zerobuf)
{
    int tid = blockIdx.x * 256 + threadIdx.x;
    int stride = gridDim.x * 256;
    // W1sw: 5 steps x 256 chunks x 8 elems (k-chunk gc -> tap=2s+(gc>>1), ch0=(gc&1)*8)
    for (int i = tid; i < 5*256*8; i += stride) {
        int e = i & 7, q = (i >> 3) & 255, s = i >> 11;
        int n = q >> 2, c = q & 3;
        int gc = c ^ ((n >> 1) & 3);
        int tap = 2*s + (gc >> 1);
        int ch = (gc & 1)*8 + e;
        float v = 0.f;
        if (tap < 9) {
            int ky = (tap*11) >> 5; int kx = tap - 3*ky;
            v = W1[((n*16 + ch)*3 + ky)*3 + kx];
        }
        W1sw[i] = f2bf(v);
    }
    // W2sw: 2 x 256 x 8 (k = s*32 + gc*8 + e)
    for (int i = tid; i < 2*256*8; i += stride) {
        int e = i & 7, q = (i >> 3) & 255, s = i >> 11;
        int n = q >> 2, c = q & 3;
        int gc = c ^ ((n >> 1) & 3);
        int k = s*32 + gc*8 + e;
        W2sw[i] = f2bf(W2[n*64 + k]);
    }
    // W3sw: 18 x 1152 x 8 ; n = ch*24+j (j==23 pad), k = s*32+gc*8+e -> tap=k>>6, ci=k&63
    for (int i = tid; i < 18*1152*8; i += stride) {
        int e = i & 7;
        int q = (i >> 3) % 1152;
        int s = i / (1152*8);
        int n = q >> 2, c = q & 3;
        int gc = c ^ ((n >> 1) & 3);
        int k = s*32 + gc*8 + e;
        int tap = k >> 6, ci = k & 63;
        int ch = n / 24, j = n - 24*ch;
        float v = 0.f;
        if (j < 23) v = W3[((ch*23 + j)*64 + ci)*9 + tap];
        W3sw[i] = f2bf(v);
    }
    for (int i = tid; i < 64; i += stride) { int4v zz = {0,0,0,0}; zerobuf[i] = zz; }
    // h2p halo zero: 16 batches x 516 border px x 8 chunks
    for (int i = tid; i < 16*516*8; i += stride) {
        int cchunk = i & 7, pxi = (i >> 3) % 516, b = i / (516*8);
        int yy, xx;
        if (pxi < 130)      { yy = 0;   xx = pxi; }
        else if (pxi < 260) { yy = 129; xx = pxi - 130; }
        else if (pxi < 388) { yy = pxi - 260 + 1; xx = 0; }
        else                { yy = pxi - 388 + 1; xx = 129; }
        int4v zz = {0,0,0,0};
        *(int4v*)(h2p + (size_t)((b*130 + yy)*130 + xx)*128 + cchunk*16) = zz;
    }
}

// ---------------------------------------------------------------------------
// pack z with 1-px halo: (16,130,130,16ch) bf16; interior ch0-11 = masked x,
// ch12-15 = cond; halo rows/cols zero. Also init logdet outputs.
// ---------------------------------------------------------------------------
__global__ __launch_bounds__(256) void pack_z(
    const float* __restrict__ x, const float* __restrict__ cond,
    const float* __restrict__ logdet_in,
    short* __restrict__ zp, float* __restrict__ logdet_out)
{
    int id = blockIdx.x * 256 + threadIdx.x;
    if (id < 16) logdet_out[id] = logdet_in[id];
    if (id >= 16*130*130) return;
    int b = id / 16900;
    int rem = id - b*16900;
    int yy = rem / 130;
    int xx = rem - yy*130;
    short vs[16];
    #pragma unroll
    for (int c = 0; c < 16; ++c) vs[c] = 0;
    if (yy >= 1 && yy <= 128 && xx >= 1 && xx <= 128) {
        int pix = (yy - 1)*128 + (xx - 1);
        bool frozen = ((yy + xx) & 1) == 1;
        #pragma unroll
        for (int c = 0; c < 12; ++c)
            vs[c] = f2bf(frozen ? x[(b*12 + c)*HW + pix] : 0.f);
        #pragma unroll
        for (int c = 0; c < 4; ++c)
            vs[12 + c] = f2bf(cond[(b*4 + c)*HW + pix]);
    }
    int4v lo = { pack2(vs[0],vs[1]),  pack2(vs[2],vs[3]),
                 pack2(vs[4],vs[5]),  pack2(vs[6],vs[7]) };
    int4v hi = { pack2(vs[8],vs[9]),  pack2(vs[10],vs[11]),
                 pack2(vs[12],vs[13]),pack2(vs[14],vs[15]) };
    *(int4v*)(zp + id*16)     = lo;
    *(int4v*)(zp + id*16 + 8) = hi;
}

// ---------------------------------------------------------------------------
// fused conv1 (3x3, 16->64) + conv2 (1x1, 64->64). Block = one image row.
// Operands swapped: A = weights (M=out-ch), B = pixels (N=px) so D cols = px.
// LDS: z-tile [128px][32k] (8K) | W [64][32k] (4K) | h1/h2 tile [128px][64ch] (16K)
// ---------------------------------------------------------------------------
__global__ __launch_bounds__(256, 4) void conv12_kernel(
    const char* __restrict__ zp, const char* __restrict__ W1sw,
    const char* __restrict__ W2sw,
    const float* __restrict__ b1, const float* __restrict__ b2,
    const char* __restrict__ zerobuf, char* __restrict__ h2p)
{
    __shared__ __align__(16) char smem[28672];
    int t = threadIdx.x;
    int lane = t & 63, w = t >> 6;
    int l15 = lane & 15, quad = lane >> 4;
    int bid = blockIdx.x;
    int b = bid >> 7, y = bid & 127;
    int chb = (w >> 1) * 32;
    int pxb = (w & 1) * 64;
    unsigned wbase = (unsigned)__builtin_amdgcn_readfirstlane(w << 10);

    // staging constants: chunk q -> px=q>>2, c=q&3, gc=c^((px>>1)&3)
    int px1 = t >> 2;
    int gc1 = (t & 3) ^ ((px1 >> 1) & 3);
    int tl1 = gc1 >> 1, zoff1 = px1*32 + (gc1 & 1)*16;
    int q2 = t + 256;
    int px2 = q2 >> 2;
    int gc2 = (q2 & 3) ^ ((px2 >> 1) & 3);
    int tl2 = gc2 >> 1, zoff2 = px2*32 + (gc2 & 1)*16;

    int waddr[2], zaddr[4];
    #pragma unroll
    for (int i = 0; i < 2; ++i) {
        int n = chb + i*16 + l15;
        waddr[i] = 8192 + n*64 + ((quad ^ ((n >> 1) & 3)) << 4);
    }
    #pragma unroll
    for (int j = 0; j < 4; ++j) {
        int px = pxb + j*16 + l15;
        zaddr[j] = px*64 + ((quad ^ ((px >> 1) & 3)) << 4);
    }

    const char* zb = zp + (size_t)(b*16900)*32;
    const float4v z4 = {0.f,0.f,0.f,0.f};
    float4v acc[2][4];
    #pragma unroll
    for (int i = 0; i < 2; ++i)
        #pragma unroll
        for (int j = 0; j < 4; ++j) acc[i][j] = z4;

    // ---- conv1: 5 K-steps of 32 (taps 2s, 2s+1; tap 9 = zero pad) ----
    for (int s = 0; s < 5; ++s) {
        __syncthreads();
        int ta = 2*s + tl1;
        const char* g1;
        if (ta < 9) { int ky = (ta*11) >> 5; int kx = ta - 3*ky;
            g1 = zb + ((y + ky)*130 + kx)*32 + zoff1; }
        else g1 = zerobuf + (lane << 4);
        async_cp16(g1, smem + wbase);
        int tb = 2*s + tl2;
        const char* g2;
        if (tb < 9) { int ky = (tb*11) >> 5; int kx = tb - 3*ky;
            g2 = zb + ((y + ky)*130 + kx)*32 + zoff2; }
        else g2 = zerobuf + (lane << 4);
        async_cp16(g2, smem + 4096 + wbase);
        async_cp16(W1sw + s*4096 + (t << 4), smem + 8192 + wbase);
        __syncthreads();
        bf16x8 aw[2];
        #pragma unroll
        for (int i = 0; i < 2; ++i) aw[i] = *(const bf16x8*)(smem + waddr[i]);
        #pragma unroll
        for (int j = 0; j < 4; ++j) {
            bf16x8 bzv = *(const bf16x8*)(smem + zaddr[j]);
            #pragma unroll
            for (int i = 0; i < 2; ++i)
                acc[i][j] = __builtin_amdgcn_mfma_f32_16x16x32_bf16(aw[i], bzv, acc[i][j], 0, 0, 0);
        }
    }
    // ---- conv1 epilogue: bias+ReLU+bf16 -> h1 tile [px][64ch], 8-chunk XOR swizzle ----
    {
        #pragma unroll
        for (int i = 0; i < 2; ++i) {
            int ch0 = chb + i*16 + quad*4;
            float bb0 = b1[ch0], bb1 = b1[ch0+1], bb2 = b1[ch0+2], bb3 = b1[ch0+3];
            #pragma unroll
            for (int j = 0; j < 4; ++j) {
                int px = pxb + j*16 + l15;
                short s0 = f2bf(fmaxf(acc[i][j][0] + bb0, 0.f));
                short s1 = f2bf(fmaxf(acc[i][j][1] + bb1, 0.f));
                short s2 = f2bf(fmaxf(acc[i][j][2] + bb2, 0.f));
                short s3 = f2bf(fmaxf(acc[i][j][3] + bb3, 0.f));
                int2v pk = { pack2(s0, s1), pack2(s2, s3) };
                *(int2v*)(smem + 12288 + px*128 + (((ch0 >> 3) ^ (px & 7)) << 4) + ((ch0 & 7) << 1)) = pk;
            }
        }
    }
    // ---- conv2: 2 K-steps of 32 ----
    float4v acc2[2][4];
    #pragma unroll
    for (int i = 0; i < 2; ++i)
        #pragma unroll
        for (int j = 0; j < 4; ++j) acc2[i][j] = z4;
    for (int s = 0; s < 2; ++s) {
        __syncthreads();
        async_cp16(W2sw + s*4096 + (t << 4), smem + 8192 + wbase);
        __syncthreads();
        bf16x8 aw[2];
        #pragma unroll
        for (int i = 0; i < 2; ++i) aw[i] = *(const bf16x8*)(smem + waddr[i]);
        #pragma unroll
        for (int j = 0; j < 4; ++j) {
            int px = pxb + j*16 + l15;
            bf16x8 bh = *(const bf16x8*)(smem + 12288 + px*128 + (((s*4 + quad) ^ (px & 7)) << 4));
            #pragma unroll
            for (int i = 0; i < 2; ++i)
                acc2[i][j] = __builtin_amdgcn_mfma_f32_16x16x32_bf16(aw[i], bh, acc2[i][j], 0, 0, 0);
        }
    }
    __syncthreads();   // all h1 reads done; reuse tile region for h2
    {
        #pragma unroll
        for (int i = 0; i < 2; ++i) {
            int ch0 = chb + i*16 + quad*4;
            float bb0 = b2[ch0], bb1 = b2[ch0+1], bb2 = b2[ch0+2], bb3 = b2[ch0+3];
            #pragma unroll
            for (int j = 0; j < 4; ++j) {
                int px = pxb + j*16 + l15;
                short s0 = f2bf(fmaxf(acc2[i][j][0] + bb0, 0.f));
                short s1 = f2bf(fmaxf(acc2[i][j][1] + bb1, 0.f));
                short s2 = f2bf(fmaxf(acc2[i][j][2] + bb2, 0.f));
                short s3 = f2bf(fmaxf(acc2[i][j][3] + bb3, 0.f));
                int2v pk = { pack2(s0, s1), pack2(s2, s3) };
                *(int2v*)(smem + 12288 + px*128 + (((ch0 >> 3) ^ (px & 7)) << 4) + ((ch0 & 7) << 1)) = pk;
            }
        }
    }
    __syncthreads();
    // copy h2 tile to global (unswizzle on LDS read; coalesced global store)
    char* dst = h2p + ((size_t)(b*130 + y + 1)*130 + 1)*128;
    #pragma unroll
    for (int u = 0; u < 4; ++u) {
        int q = t + u*256;
        int px = q >> 3, g = q & 7;
        int4v v = *(const int4v*)(smem + 12288 + px*128 + ((g ^ (px & 7)) << 4));
        *(int4v*)(dst + px*128 + (g << 4)) = v;
    }
}

// ---------------------------------------------------------------------------
// conv3 (3x3, 64 -> 276 pad 288) fused with RQS + logdet.
// Block = one row, 384 threads = 6 waves: (px-half 2) x (col-group-of-96 3).
// A = pixels (M), B = weights (N). 18 K-steps of 32.
// RQS evaluated at ALL pixels (frozen pixels use x_active = 0, per reference:
// their y(0) adds to x_out and lad(0) adds to logdet).
// ---------------------------------------------------------------------------
__global__ __launch_bounds__(384, 3) void conv3_rqs_kernel(
    const char* __restrict__ h2p, const char* __restrict__ W3sw,
    const float* __restrict__ b3, const float* __restrict__ x,
    float* __restrict__ out, float* __restrict__ logdet_out)
{
    __shared__ __align__(16) char smem[39552];
    // [0,8192) A-tile | [8192,26624) B-tile | epilogue: [0,38400) scratch
    // [38400,39504) b3 bias
    int t = threadIdx.x;
    int lane = t & 63, w = t >> 6;
    int l15 = lane & 15, quad = lane >> 4;
    int bid = blockIdx.x;
    int b = bid >> 7, y = bid & 127;

    float* b3s = (float*)(smem + 38400);
    if (t < 276) b3s[t] = b3[t];

    int p = (w >= 3) ? 1 : 0;
    int colg = w - 3*p;
    int pxb = p << 6;
    int cb = colg * 96;

    int aaddr[4], baddr[6];
    #pragma unroll
    for (int i = 0; i < 4; ++i) {
        int row = pxb + i*16 + l15;
        aaddr[i] = row*64 + ((quad ^ ((row >> 1) & 3)) << 4);
    }
    #pragma unroll
    for (int j = 0; j < 6; ++j) {
        int n = cb + j*16 + l15;
        baddr[j] = 8192 + n*64 + ((quad ^ ((n >> 1) & 3)) << 4);
    }

    int px1 = t >> 2;
    int gc1 = (t & 3) ^ ((px1 >> 1) & 3);
    int off1 = px1*128 + gc1*16;
    int q2i = 384 + t;
    int px2i = q2i >> 2;
    int gc2 = (q2i & 3) ^ ((px2i >> 1) & 3);
    int off2 = px2i*128 + gc2*16;
    unsigned wbase = (unsigned)__builtin_amdgcn_readfirstlane(w << 10);

    const float4v z4 = {0.f,0.f,0.f,0.f};
    float4v acc[4][6];
    #pragma unroll
    for (int i = 0; i < 4; ++i)
        #pragma unroll
        for (int j = 0; j < 6; ++j) acc[i][j] = z4;

    const char* h2pb = h2p + (size_t)(b*130)*130*128;
    for (int s = 0; s < 18; ++s) {
        int tap = s >> 1, kh = s & 1;
        int td3 = (tap*11) >> 5;
        int tm3 = tap - 3*td3;
        const char* sbA = h2pb + ((y + td3)*130 + tm3)*128 + kh*64;
        const char* sbB = W3sw + s*18432;
        __syncthreads();
        async_cp16(sbA + off1, smem + wbase);
        if (w < 2) async_cp16(sbA + off2, smem + 6144 + wbase);
        async_cp16(sbB + (t << 4),         smem + 8192 + wbase);
        async_cp16(sbB + 6144 + (t << 4),  smem + 14336 + wbase);
        async_cp16(sbB + 12288 + (t << 4), smem + 20480 + wbase);
        __syncthreads();
        bf16x8 av[4];
        #pragma unroll
        for (int i = 0; i < 4; ++i) av[i] = *(const bf16x8*)(smem + aaddr[i]);
        #pragma unroll
        for (int j = 0; j < 6; ++j) {
            bf16x8 bv = *(const bf16x8*)(smem + baddr[j]);
            #pragma unroll
            for (int i = 0; i < 4; ++i)
                acc[i][j] = __builtin_amdgcn_mfma_f32_16x16x32_bf16(av[i], bv, acc[i][j], 0, 0, 0);
        }
    }
    __syncthreads();   // staging regions -> per-wave epilogue scratch

    // ---------------- epilogue: full-pixel RQS ----------------
    float* scr = (float*)smem + w * 1600;   // 16 rows x 100 floats per wave
    float ldsum = 0.f;
    int pxh = l15;
    int cidx = quad;
    int c = colg*4 + cidx;
    const float* bb3 = b3s + c*23;

    #pragma unroll 1
    for (int dri = 0; dri < 4; ++dri) {
        // stash this 16-px quarter, all 96 cols (D: row m = quad*4+r, col = l15)
        #pragma unroll
        for (int r = 0; r < 4; ++r) {
            int sr = quad*4 + r;
            #pragma unroll
            for (int j = 0; j < 6; ++j)
                scr[sr*100 + j*16 + l15] = acc[dri][j][r];
        }
        // per-wave private scratch: same-wave DS ordering suffices (no barrier)
        const float* P = scr + pxh*100 + cidx*24;
        float pr[24];
        *(float4v*)&pr[0]  = *(const float4v*)(P);
        *(float4v*)&pr[4]  = *(const float4v*)(P + 4);
        *(float4v*)&pr[8]  = *(const float4v*)(P + 8);
        *(float4v*)&pr[12] = *(const float4v*)(P + 12);
        *(float4v*)&pr[16] = *(const float4v*)(P + 16);
        *(float4v*)&pr[20] = *(const float4v*)(P + 20);
        float pa[23];
        #pragma unroll
        for (int j = 0; j < 23; ++j) pa[j] = pr[j] + bb3[j];

        int px = pxb + dri*16 + pxh;
        int gidx = ((b*12 + c) << 14) + (y << 7) + px;
        float xin = x[gidx];
        bool frozen = ((y + px) & 1) == 1;
        float xa = frozen ? 0.f : xin;
        float xf = frozen ? xin : 0.f;
        float xc = fminf(fmaxf(xa, -3.f), 3.f);
        bool inside = (xa >= -3.f) && (xa <= 3.f);

        // widths softmax + cumwidths + bin select
        float mw = pa[0];
        #pragma unroll
        for (int j = 1; j < 8; ++j) mw = fmaxf(mw, pa[j]);
        float ew[8]; float sw = 0.f;
        #pragma unroll
        for (int j = 0; j < 8; ++j) { ew[j] = __expf(pa[j] - mw); sw += ew[j]; }
        float Aw = 0.992f / sw;
        float run = 0.f, cwl = -3.f, icw = -3.f, iwid = 1.f;
        int idx = 0;
        #pragma unroll
        for (int j = 0; j < 8; ++j) {
            float wj = fmaf(Aw, ew[j], 0.001f);
            run += wj;
            float cwr = (j == 7) ? 3.f : fmaf(6.f, run, -3.f);
            if (xc >= cwl) { icw = cwl; iwid = cwr - cwl; idx = j; }
            cwl = cwr;
        }
        // heights softmax + cumheights at idx
        float mh = pa[8];
        #pragma unroll
        for (int j = 9; j < 16; ++j) mh = fmaxf(mh, pa[j]);
        float eh[8]; float sh = 0.f;
        #pragma unroll
        for (int j = 0; j < 8; ++j) { eh[j] = __expf(pa[8 + j] - mh); sh += eh[j]; }
        float Ah = 0.992f / sh;
        run = 0.f;
        float chl = -3.f, ich = 0.f, ihei = 1.f;
        #pragma unroll
        for (int j = 0; j < 8; ++j) {
            float hj = fmaf(Ah, eh[j], 0.001f);
            run += hj;
            float chr = (j == 7) ? 3.f : fmaf(6.f, run, -3.f);
            if (j == idx) { ich = chl; ihei = chr - chl; }
            chl = chr;
        }
        // derivatives: select raw params for slots idx, idx+1; softplus only those
        // (d[0]=d[8]=1 exactly: MD + softplus(log(expm1(1-MD))) = 1)
        float v0 = 0.f, v1 = 0.f;
        bool h0 = false, h1 = false;
        #pragma unroll
        for (int j = 1; j < 8; ++j) {
            float v = pa[15 + j];
            if (j == idx)     { v0 = v; h0 = true; }
            if (j == idx + 1) { v1 = v; h1 = true; }
        }
        float sp0 = (v0 > 15.f) ? v0 : __logf(1.f + __expf(v0));
        float sp1 = (v1 > 15.f) ? v1 : __logf(1.f + __expf(v1));
        float d0 = h0 ? (0.001f + sp0) : 1.f;
        float d1 = h1 ? (0.001f + sp1) : 1.f;

        float dl = ihei / iwid;
        float th = (xc - icw) / iwid;
        float omt = 1.f - th;
        float t1 = th * omt;
        float num = ihei * (dl*th*th + d0*t1);
        float den = dl + (d0 + d1 - 2.f*dl)*t1;
        float yv = ich + num/den;
        float dnum = dl*dl*(d1*th*th + 2.f*dl*t1 + d0*omt*omt);
        float lad = __logf(dnum) - 2.f*__logf(den);

        out[gidx] = xf + (inside ? yv : xa);
        ldsum += inside ? lad : 0.f;
    }
    #pragma unroll
    for (int off = 32; off > 0; off >>= 1)
        ldsum += __shfl_down(ldsum, off, 64);
    if (lane == 0) atomicAdd(logdet_out + b, ldsum);
}

// ---------------------------------------------------------------------------
extern "C" void kernel_launch(void* const* d_in, const int* in_sizes, int n_in,
                              void* d_out, int out_size, void* d_ws, size_t ws_size,
                              hipStream_t stream)
{
    (void)in_sizes; (void)n_in; (void)out_size; (void)ws_size;
    const float* x    = (const float*)d_in[0];
    const float* ld   = (const float*)d_in[1];
    const float* cond = (const float*)d_in[2];
    const float* W1   = (const float*)d_in[3];
    const float* b1   = (const float*)d_in[4];
    const float* W2   = (const float*)d_in[5];
    const float* b2   = (const float*)d_in[6];
    const float* W3   = (const float*)d_in[7];
    const float* b3   = (const float*)d_in[8];
    float* out = (float*)d_out;
    char* ws = (char*)d_ws;

    short* zp   = (short*)(ws);                //  8,652,800 B  (16,130,130,16) bf16
    char*  h2p  = ws + 8652800;                // 34,611,200 B  (16,130,130,64) bf16
    short* W1sw = (short*)(ws + 43264000);     //     20,480 B
    short* W2sw = (short*)(ws + 43284480);     //      8,192 B
    short* W3sw = (short*)(ws + 43292672);     //    331,776 B
    char*  zerob= ws + 43624448;               //      1,024 B
    float* ldout = out + 12*HW*16;

    prep_weights<<<dim3(256), dim3(256), 0, stream>>>(
        W1, W2, W3, W1sw, W2sw, W3sw, h2p, (int4v*)zerob);
    pack_z<<<dim3(1057), dim3(256), 0, stream>>>(x, cond, ld, zp, ldout);
    conv12_kernel<<<dim3(2048), dim3(256), 0, stream>>>(
        (const char*)zp, (const char*)W1sw, (const char*)W2sw, b1, b2,
        (const char*)zerob, h2p);
    conv3_rqs_kernel<<<dim3(2048), dim3(384), 0, stream>>>(
        (const char*)h2p, (const char*)W3sw, b3, x, out, ldout);
}